// Round 1
// baseline (394.480 us; speedup 1.0000x reference)
//
#include <hip/hip_runtime.h>
#include <math.h>

// ---------------- problem constants ----------------
#define FC     65            // freq bins in H
#define NB     97            // output samples per frame (lossy irfft n)
#define KB     49            // bins actually used = NB//2+1
#define FRAME  64
#define B_     32
#define F_     4000
#define OUT_LEN ((F_ - 1) * FRAME + NB)   // 256033
#define CHUNK  64                          // frames per block (one wave)
#define NCHUNK ((F_ + CHUNK - 1) / CHUNK)  // 63
#define KP     98                          // row stride: 49 complex = 98 floats

// ws layout (floats):
//   D: [64][98]  row j: (cos, -sin)(2*pi*k*j/192) pairs, k=0..48
//   W: [65][98]  row kappa: complex of sum_m a(m,kappa) e^{-2pi i k m/192}
//   E: [97][98]  row t: (Er, Ei) pairs, gain folded in
#define D_OFF  0
#define W_OFF  (64 * KP)                   // 6272
#define E_OFF  (W_OFF + 65 * KP)           // 12642
#define WS_FLOATS (E_OFF + 97 * KP)        // 22148 floats = 86.5 KB

#define N_D    (64 * KB)                   // 3136
#define N_W    (65 * KB)                   // 3185
#define N_E    (97 * KB)                   // 4753
#define N_MAT  (N_D + N_W + N_E)           // 11074
#define N_ZERO (B_ * 64 * 33)              // 67584 boundary-stripe zeros
#define INIT_THREADS (N_MAT + N_ZERO)

__global__ void fn_init_kernel(float* __restrict__ ws, float* __restrict__ out) {
    int tid = blockIdx.x * blockDim.x + threadIdx.x;
    if (tid < N_D) {
        int j = tid / KB, k = tid % KB;
        double th = -2.0 * M_PI * (double)(k * j) / 192.0;
        ws[D_OFF + j * KP + 2 * k]     = (float)cos(th);
        ws[D_OFF + j * KP + 2 * k + 1] = (float)sin(th);
    } else if (tid < N_D + N_W) {
        int t2 = tid - N_D;
        int kap = t2 / KB, k = t2 % KB;
        double sr = 0.0, si = 0.0;
        for (int m = 0; m < 129; m++) {
            double win = 0.5 * (1.0 - cos(2.0 * M_PI * (double)m / 129.0));
            double a = win * (1.0 / 129.0) *
                       (kap == 0 ? 1.0 : 2.0 * cos(2.0 * M_PI * (double)(kap * (m - 64)) / 129.0));
            double th = -2.0 * M_PI * (double)(k * m) / 192.0;
            sr += a * cos(th);
            si += a * sin(th);
        }
        ws[W_OFF + kap * KP + 2 * k]     = (float)sr;
        ws[W_OFF + kap * KP + 2 * k + 1] = (float)si;
    } else if (tid < N_MAT) {
        int t2 = tid - (N_D + N_W);
        int t = t2 / KB, k = t2 % KB;
        double g = 0.01 / 97.0;
        double c = cos(2.0 * M_PI * (double)(k * t) / 97.0);
        double s = sin(2.0 * M_PI * (double)(k * t) / 97.0);
        ws[E_OFF + t * KP + 2 * k]     = (float)(g * (k == 0 ? 1.0 : 2.0) * c);
        ws[E_OFF + t * KP + 2 * k + 1] = (float)(k == 0 ? 0.0 : -g * 2.0 * s);
    } else if (tid < INIT_THREADS) {
        // zero only the 33-sample boundary stripes that receive atomics
        int z = tid - N_MAT;
        int b = z / (64 * 33);
        int r = z % (64 * 33);
        int sidx = r / 33;
        int o = r % 33;
        long start = (sidx == 63) ? 256000L : (long)sidx * 4096L;
        out[(long)b * OUT_LEN + start + o] = 0.0f;
    }
}

__launch_bounds__(64, 2)
__global__ void fn_main_kernel(const float* __restrict__ H,
                               const float* __restrict__ noise,
                               const float* __restrict__ ws,
                               float* __restrict__ out) {
    __shared__ float lds[4160];   // reused: noise(64x65 padded) -> H(65x64 linear) -> ybuf(64x34)

    int bid = blockIdx.x;
    int b = bid / NCHUNK;
    int c = bid % NCHUNK;
    int f0 = c * CHUNK;
    int cF = min(CHUNK, F_ - f0);
    int L = threadIdx.x;          // lane == frame-within-chunk

    // ---- phase 0: stage noise (transformed to 2n-1), padded stride 65 ----
    long nbase = ((long)b * F_ + f0) * FRAME;
    long nmax = (long)B_ * F_ * FRAME - 1;
    for (int i = 0; i < 64; i++) {
        long g = nbase + (long)i * 64 + L;
        if (g > nmax) g = nmax;
        lds[i * 65 + L] = 2.0f * noise[g] - 1.0f;
    }
    __syncthreads();

    // ---- phase 1: N[k] = DFT_192 of 64-sample frame, bins 0..48 ----
    float Nr[KB], Ni[KB];
#pragma unroll
    for (int k = 0; k < KB; k++) { Nr[k] = 0.0f; Ni[k] = 0.0f; }
    for (int j = 0; j < 64; j++) {
        float n = lds[L * 65 + j];
        const float* d = ws + D_OFF + j * KP;
#pragma unroll
        for (int k = 0; k < KB; k++) {
            Nr[k] = fmaf(n, d[2 * k],     Nr[k]);
            Ni[k] = fmaf(n, d[2 * k + 1], Ni[k]);
        }
    }
    __syncthreads();

    // ---- phase 2: stage H, linear (stride 65 rows contiguous) ----
    long hbase = ((long)b * F_ + f0) * FC;
    long hmax = (long)B_ * F_ * FC - 1;
    for (int i = 0; i < 65; i++) {
        long g = hbase + (long)i * 64 + L;
        if (g > hmax) g = hmax;
        lds[i * 64 + L] = H[g];
    }
    __syncthreads();

    // ---- phase 3: IR[k] = W . H ----
    float Rr[KB], Ri[KB];
#pragma unroll
    for (int k = 0; k < KB; k++) { Rr[k] = 0.0f; Ri[k] = 0.0f; }
    for (int kap = 0; kap < FC; kap++) {
        float h = lds[L * FC + kap];
        const float* w = ws + W_OFF + kap * KP;
#pragma unroll
        for (int k = 0; k < KB; k++) {
            Rr[k] = fmaf(h, w[2 * k],     Rr[k]);
            Ri[k] = fmaf(h, w[2 * k + 1], Ri[k]);
        }
    }

    // ---- phase 4: X = N * IR (complex), in place into Nr/Ni ----
#pragma unroll
    for (int k = 0; k < KB; k++) {
        float xr = Nr[k] * Rr[k] - Ni[k] * Ri[k];
        float xi = Nr[k] * Ri[k] + Ni[k] * Rr[k];
        Nr[k] = xr; Ni[k] = xi;
    }
    __syncthreads();   // H buffer dead; reuse lds as ybuf head storage

    // ---- phase 5: y[t] = E[t] . X, streamed; in-wave overlap-add ----
    long obase = (long)b * OUT_LEN + (long)f0 * FRAME;
    int lastLane = cF - 1;
    bool valid = (L < cF);

    for (int t = 0; t < NB; t++) {
        const float* e = ws + E_OFF + t * KP;
        float y0 = 0.0f, y1 = 0.0f, y2 = 0.0f, y3 = 0.0f;
#pragma unroll
        for (int k = 0; k < 48; k += 4) {
            y0 = fmaf(Nr[k],     e[2 * k],     y0); y0 = fmaf(Ni[k],     e[2 * k + 1], y0);
            y1 = fmaf(Nr[k + 1], e[2 * k + 2], y1); y1 = fmaf(Ni[k + 1], e[2 * k + 3], y1);
            y2 = fmaf(Nr[k + 2], e[2 * k + 4], y2); y2 = fmaf(Ni[k + 2], e[2 * k + 5], y2);
            y3 = fmaf(Nr[k + 3], e[2 * k + 6], y3); y3 = fmaf(Ni[k + 3], e[2 * k + 7], y3);
        }
        y0 = fmaf(Nr[48], e[96], y0);
        y0 = fmaf(Ni[48], e[97], y0);
        float y = (y0 + y1) + (y2 + y3);

        if (t < 33) {
            // head samples overlap previous frame's tail: buffer them
            lds[L * 34 + t] = y;
        } else if (t < 64) {
            // exclusive samples: direct store
            if (valid) out[obase + 64L * 0 + (long)64 * L + t] = y;
        } else {
            int r = t - 64;
            float p = __shfl_up(y, 1);       // previous frame's tail sample
            float own = lds[L * 34 + r];      // this frame's buffered head sample
            if (valid) {
                if (L == 0) {
                    // needs previous chunk's tail -> atomic into zeroed stripe
                    atomicAdd(&out[obase + r], own);
                } else {
                    out[obase + (long)64 * L + r] = own + p;
                }
                if (L == lastLane) {
                    // this chunk's tail spills into next chunk's head stripe
                    atomicAdd(&out[obase + (long)64 * cF + r], y);
                }
            }
        }
    }
}

extern "C" void kernel_launch(void* const* d_in, const int* in_sizes, int n_in,
                              void* d_out, int out_size, void* d_ws, size_t ws_size,
                              hipStream_t stream) {
    const float* H     = (const float*)d_in[0];   // (32, 4000, 65) fp32
    const float* noise = (const float*)d_in[1];   // (32, 4000, 64) fp32
    float* out = (float*)d_out;                   // (32, 256033) fp32
    float* ws  = (float*)d_ws;                    // matrices, 22148 floats

    int init_blocks = (INIT_THREADS + 255) / 256;
    fn_init_kernel<<<init_blocks, 256, 0, stream>>>(ws, out);

    int main_blocks = B_ * NCHUNK;                // 2016 blocks x 64 threads
    fn_main_kernel<<<main_blocks, 64, 0, stream>>>(H, noise, ws, out);
}